// Round 10
// baseline (741.623 us; speedup 1.0000x reference)
//
#include <hip/hip_runtime.h>
#include <hip/hip_bf16.h>

#define TLEN 16384
#define NB 4
#define NLAYER 50
#define SUMD 5115
#define LOUT 11269                  // TLEN - SUMD
#define K1 (NLAYER * 32)            // 1600
#define MSKIP 512
#define FWOUT 256                   // fused-kernel owned points per block
#define FWIN 511                    // FWOUT + 255 halo
#define FP 34                       // padded LDS row stride (floats); 34%32=2 -> distinct banks

typedef unsigned short u16;
typedef __attribute__((ext_vector_type(4))) float f32x4;
typedef __attribute__((ext_vector_type(8))) __bf16 bf16x8;

__device__ __forceinline__ u16 f2bf(float f) {
  __hip_bfloat16 h = __float2bfloat16(f);
  return *reinterpret_cast<u16*>(&h);
}
__device__ __forceinline__ float bf2f(u16 u) {
  __hip_bfloat16 h = *reinterpret_cast<__hip_bfloat16*>(&u);
  return __bfloat162float(h);
}

// ---------- prep: convert/pack weights (once per call) ----------
__global__ __launch_bounds__(256) void prep_k(
    const float* __restrict__ skip_w, const float* __restrict__ skip_b,
    const float* __restrict__ post1_w,
    const float* __restrict__ sig_w, const float* __restrict__ tan_w,
    const float* __restrict__ res_w,
    u16* __restrict__ Wskip, u16* __restrict__ P1, float* __restrict__ biasS,
    u16* __restrict__ WC, u16* __restrict__ RC) {
  int t = blockIdx.x * 256 + threadIdx.x;
  const int n1 = 512 * K1;
  const int n2 = n1 + 512 * 512;
  const int n3 = n2 + 512;
  const int n4 = n3 + NLAYER * 64 * 64;
  const int n5 = n4 + NLAYER * 32 * 32;
  if (t < n1) {
    int m = t / K1, k = t - m * K1;
    int i = k >> 5, c = k & 31;
    Wskip[t] = f2bf(skip_w[((size_t)i * 512 + m) * 32 + c]);
  } else if (t < n2) {
    int z = t - n1;
    P1[z] = f2bf(post1_w[z]);
  } else if (t < n3) {
    int c = t - n2;
    float s = 0.f;
    for (int i = 0; i < NLAYER; i++) s += skip_b[i * 512 + c];
    biasS[c] = s;
  } else if (t < n4) {
    int z = t - n3;
    int l = z >> 12, rem = z & 4095, o = rem >> 6, k = rem & 63;
    int c = k & 31, lr = k >> 5;
    float v;
    if (o < 32) v = sig_w[(((size_t)l * 32 + o) * 32 + c) * 2 + lr];
    else        v = tan_w[(((size_t)l * 32 + (o - 32)) * 32 + c) * 2 + lr];
    WC[z] = f2bf(v);
  } else if (t < n5) {
    int z = t - n4;
    int l = z >> 10, rem = z & 1023, o = rem >> 5, c = rem & 31;
    RC[z] = f2bf(res_w[((size_t)l * 32 + o) * 32 + c]);
  }
}

// ---------- init (point-major H [b][p][32]): h0 = from_w @ input + from_b ----------
__global__ __launch_bounds__(256) void init_p(
    const float* __restrict__ inp, const float* __restrict__ fw,
    const float* __restrict__ fb, float* __restrict__ H, int t0, int cw) {
  __shared__ float FWs[256];
  __shared__ float FBs[32];
  int tid = threadIdx.x;
  FWs[tid] = fw[tid];
  if (tid < 32) FBs[tid] = fb[tid];
  __syncthreads();
  int gsz = gridDim.x * 256;
  int gid0 = blockIdx.x * 256 + tid;
  for (int b = 0; b < NB; b++) {
    const float* ib = inp + ((size_t)b * TLEN + t0) * 8;
    float* hb = H + (size_t)b * cw * 32;
    for (int p = gid0; p < cw; p += gsz) {
      float4 x0 = *reinterpret_cast<const float4*>(ib + (size_t)p * 8);
      float4 x1 = *reinterpret_cast<const float4*>(ib + (size_t)p * 8 + 4);
      float x[8] = {x0.x, x0.y, x0.z, x0.w, x1.x, x1.y, x1.z, x1.w};
      float* op = hb + (size_t)p * 32;
      #pragma unroll
      for (int r4 = 0; r4 < 8; r4++) {
        float4 o;
        #pragma unroll
        for (int j = 0; j < 4; j++) {
          int r = r4 * 4 + j;
          float acc = FBs[r];
          #pragma unroll
          for (int f = 0; f < 8; f++) acc += FWs[r * 8 + f] * x[f];
          ((float*)&o)[j] = acc;
        }
        *reinterpret_cast<float4*>(op + r4 * 4) = o;
      }
    }
  }
}

// ---------- fused 8 small-dilation layers (d = 1..128, halo 255) in LDS ----------
// 1024 thr = 16 waves = 4 waves/SIMD at 1 block/CU (LDS 159.5 KB).
__global__ __launch_bounds__(1024, 1) void fuse8_k(
    const float* __restrict__ src, float* __restrict__ dst,
    u16* __restrict__ G,
    const u16* __restrict__ WC, const u16* __restrict__ RC,
    const float* __restrict__ sb, const float* __restrict__ tb,
    const float* __restrict__ rb,
    int L0, int len_in, int cw, int clen) {
  __shared__ float HB[2][FWIN][FP];   // 139.0 KB
  __shared__ u16 GT[16][16][40];      // 20.5 KB
  int tid = threadIdx.x;
  int wv = tid >> 6, lane = tid & 63;
  int pc = lane & 15, kg = lane >> 4;
  int b = blockIdx.y;
  int len_out = len_in - 255;
  int pstart = cw - len_out + blockIdx.x * FWOUT;
  int g0 = pstart - 255;
  int wcount = (cw - g0 < FWIN) ? (cw - g0) : FWIN;
  int ocount = (cw - pstart < FWOUT) ? (cw - pstart) : FWOUT;

  const float* sp = src + ((size_t)b * cw + g0) * 32;
  for (int z = tid; z < wcount * 8; z += 1024) {
    int lp = z >> 3, c4 = z & 7;
    *reinterpret_cast<float4*>(&HB[0][lp][c4 * 4]) =
        *reinterpret_cast<const float4*>(sp + (size_t)lp * 32 + c4 * 4);
  }
  __syncthreads();

  int cur = 0;
  for (int l = 0; l < 8; l++) {
    int d = 1 << l;
    int cumD = (2 << l) - 1;
    const u16* Wc = WC + (size_t)(L0 + l) * 4096;
    const u16* Rc = RC + (size_t)(L0 + l) * 1024;
    bf16x8 AW[4][2], AR[2];
    #pragma unroll
    for (int mt = 0; mt < 4; mt++) {
      AW[mt][0] = *reinterpret_cast<const bf16x8*>(Wc + (mt * 16 + pc) * 64 + kg * 8);
      AW[mt][1] = *reinterpret_cast<const bf16x8*>(Wc + (mt * 16 + pc) * 64 + 32 + kg * 8);
    }
    AR[0] = *reinterpret_cast<const bf16x8*>(Rc + pc * 32 + kg * 8);
    AR[1] = *reinterpret_cast<const bf16x8*>(Rc + (16 + pc) * 32 + kg * 8);
    float4 sbv0 = *reinterpret_cast<const float4*>(sb + (L0 + l) * 32 + kg * 4);
    float4 sbv1 = *reinterpret_cast<const float4*>(sb + (L0 + l) * 32 + 16 + kg * 4);
    float4 tbv0 = *reinterpret_cast<const float4*>(tb + (L0 + l) * 32 + kg * 4);
    float4 tbv1 = *reinterpret_cast<const float4*>(tb + (L0 + l) * 32 + 16 + kg * 4);
    float4 rbv0 = *reinterpret_cast<const float4*>(rb + (L0 + l) * 32 + kg * 4);
    float4 rbv1 = *reinterpret_cast<const float4*>(rb + (L0 + l) * 32 + 16 + kg * 4);

    int lo_local = wcount - cumD;
    int nit = (lo_local + 255) >> 8;    // 16 waves x 16 pts = 256/iter
    for (int t = 0; t < nit; t++) {
      int lp = cumD + t * 256 + wv * 16 + pc;
      bool valid = lp < wcount;
      int lpc = valid ? lp : wcount - 1;

      float4 r0 = *reinterpret_cast<const float4*>(&HB[cur][lpc][kg * 8]);
      float4 r1 = *reinterpret_cast<const float4*>(&HB[cur][lpc][kg * 8 + 4]);
      float4 l0v = *reinterpret_cast<const float4*>(&HB[cur][lpc - d][kg * 8]);
      float4 l1v = *reinterpret_cast<const float4*>(&HB[cur][lpc - d][kg * 8 + 4]);

      union { u16 u[8]; bf16x8 v; } uL, uR;
      {
        float lf[8] = {l0v.x, l0v.y, l0v.z, l0v.w, l1v.x, l1v.y, l1v.z, l1v.w};
        float rf[8] = {r0.x, r0.y, r0.z, r0.w, r1.x, r1.y, r1.z, r1.w};
        #pragma unroll
        for (int j = 0; j < 8; j++) { uL.u[j] = f2bf(lf[j]); uR.u[j] = f2bf(rf[j]); }
      }

      f32x4 cs0 = {0.f, 0.f, 0.f, 0.f}, cs1 = {0.f, 0.f, 0.f, 0.f};
      f32x4 ct0 = {0.f, 0.f, 0.f, 0.f}, ct1 = {0.f, 0.f, 0.f, 0.f};
      cs0 = __builtin_amdgcn_mfma_f32_16x16x32_bf16(AW[0][0], uL.v, cs0, 0, 0, 0);
      cs0 = __builtin_amdgcn_mfma_f32_16x16x32_bf16(AW[0][1], uR.v, cs0, 0, 0, 0);
      cs1 = __builtin_amdgcn_mfma_f32_16x16x32_bf16(AW[1][0], uL.v, cs1, 0, 0, 0);
      cs1 = __builtin_amdgcn_mfma_f32_16x16x32_bf16(AW[1][1], uR.v, cs1, 0, 0, 0);
      ct0 = __builtin_amdgcn_mfma_f32_16x16x32_bf16(AW[2][0], uL.v, ct0, 0, 0, 0);
      ct0 = __builtin_amdgcn_mfma_f32_16x16x32_bf16(AW[2][1], uR.v, ct0, 0, 0, 0);
      ct1 = __builtin_amdgcn_mfma_f32_16x16x32_bf16(AW[3][0], uL.v, ct1, 0, 0, 0);
      ct1 = __builtin_amdgcn_mfma_f32_16x16x32_bf16(AW[3][1], uR.v, ct1, 0, 0, 0);

      u16 gs0[4], gs1[4];
      {
        float sa[4] = {sbv0.x, sbv0.y, sbv0.z, sbv0.w};
        float sbq[4] = {sbv1.x, sbv1.y, sbv1.z, sbv1.w};
        float ta[4] = {tbv0.x, tbv0.y, tbv0.z, tbv0.w};
        float tbq[4] = {tbv1.x, tbv1.y, tbv1.z, tbv1.w};
        #pragma unroll
        for (int r = 0; r < 4; r++) {
          float s0 = cs0[r] + sa[r], t0v = ct0[r] + ta[r];
          float s1 = cs1[r] + sbq[r], t1v = ct1[r] + tbq[r];
          float g0v = (1.f / (1.f + __expf(-s0))) * (2.f / (1.f + __expf(-2.f * t0v)) - 1.f);
          float g1v = (1.f / (1.f + __expf(-s1))) * (2.f / (1.f + __expf(-2.f * t1v)) - 1.f);
          gs0[r] = f2bf(g0v);
          gs1[r] = f2bf(g1v);
        }
      }
      uint2 pk0 = {(unsigned)gs0[0] | ((unsigned)gs0[1] << 16),
                   (unsigned)gs0[2] | ((unsigned)gs0[3] << 16)};
      uint2 pk1 = {(unsigned)gs1[0] | ((unsigned)gs1[1] << 16),
                   (unsigned)gs1[2] | ((unsigned)gs1[3] << 16)};
      *reinterpret_cast<uint2*>(&GT[wv][pc][kg * 4]) = pk0;
      *reinterpret_cast<uint2*>(&GT[wv][pc][16 + kg * 4]) = pk1;

      int p = g0 + lpc;
      if (valid && p >= pstart && p < pstart + ocount && p >= cw - clen) {
        int n = b * clen + (p - (cw - clen));
        u16* gr = G + (size_t)n * K1 + (L0 + l) * 32;
        *reinterpret_cast<uint2*>(gr + kg * 4) = pk0;
        *reinterpret_cast<uint2*>(gr + 16 + kg * 4) = pk1;
      }

      bf16x8 bg = *reinterpret_cast<const bf16x8*>(&GT[wv][pc][kg * 8]);
      float4 ha = *reinterpret_cast<const float4*>(&HB[cur][lpc][kg * 4]);
      float4 hb2 = *reinterpret_cast<const float4*>(&HB[cur][lpc][16 + kg * 4]);
      f32x4 h0 = {ha.x + rbv0.x, ha.y + rbv0.y, ha.z + rbv0.z, ha.w + rbv0.w};
      f32x4 h1 = {hb2.x + rbv1.x, hb2.y + rbv1.y, hb2.z + rbv1.z, hb2.w + rbv1.w};
      f32x4 d0 = __builtin_amdgcn_mfma_f32_16x16x32_bf16(AR[0], bg, h0, 0, 0, 0);
      f32x4 d1 = __builtin_amdgcn_mfma_f32_16x16x32_bf16(AR[1], bg, h1, 0, 0, 0);
      if (valid) {
        *reinterpret_cast<float4*>(&HB[cur ^ 1][lp][kg * 4]) = float4{d0[0], d0[1], d0[2], d0[3]};
        *reinterpret_cast<float4*>(&HB[cur ^ 1][lp][16 + kg * 4]) = float4{d1[0], d1[1], d1[2], d1[3]};
      }
    }
    __syncthreads();
    cur ^= 1;
  }

  float* dp = dst + ((size_t)b * cw + pstart) * 32;
  for (int z = tid; z < ocount * 8; z += 1024) {
    int lp = z >> 3, c4 = z & 7;
    *reinterpret_cast<float4*>(dp + (size_t)lp * 32 + c4 * 4) =
        *reinterpret_cast<float4*>(&HB[cur][255 + lp][c4 * 4]);
  }
}

// ---------- single big-dilation layer (point-major) ----------
__global__ __launch_bounds__(256, 2) void layer_p(
    const float* __restrict__ src, float* __restrict__ dst,
    u16* __restrict__ G,
    const u16* __restrict__ Wc, const u16* __restrict__ Rc,
    const float* __restrict__ sbl, const float* __restrict__ tbl,
    const float* __restrict__ rbl,
    int layer, int d, int lo, int cw, int clen) {
  __shared__ u16 GT[4][16][40];
  __shared__ float HRT[4][16][36];
  int tid = threadIdx.x;
  int wv = tid >> 6, lane = tid & 63;
  int pc = lane & 15, kg = lane >> 4;
  int b = blockIdx.y;

  bf16x8 AW[4][2], AR[2];
  #pragma unroll
  for (int mt = 0; mt < 4; mt++) {
    AW[mt][0] = *reinterpret_cast<const bf16x8*>(Wc + (mt * 16 + pc) * 64 + kg * 8);
    AW[mt][1] = *reinterpret_cast<const bf16x8*>(Wc + (mt * 16 + pc) * 64 + 32 + kg * 8);
  }
  AR[0] = *reinterpret_cast<const bf16x8*>(Rc + pc * 32 + kg * 8);
  AR[1] = *reinterpret_cast<const bf16x8*>(Rc + (16 + pc) * 32 + kg * 8);

  float4 sbv0 = *reinterpret_cast<const float4*>(sbl + kg * 4);
  float4 sbv1 = *reinterpret_cast<const float4*>(sbl + 16 + kg * 4);
  float4 tbv0 = *reinterpret_cast<const float4*>(tbl + kg * 4);
  float4 tbv1 = *reinterpret_cast<const float4*>(tbl + 16 + kg * 4);
  float4 rbv0 = *reinterpret_cast<const float4*>(rbl + kg * 4);
  float4 rbv1 = *reinterpret_cast<const float4*>(rbl + 16 + kg * 4);

  int idx = blockIdx.x * 64 + wv * 16 + pc;
  bool valid = idx < lo;
  int idc = valid ? idx : lo - 1;
  int p = cw - lo + idc;

  const float* hp = src + ((size_t)b * cw + p) * 32 + kg * 8;
  float4 r0 = *reinterpret_cast<const float4*>(hp);
  float4 r1 = *reinterpret_cast<const float4*>(hp + 4);
  const float* hq = hp - (size_t)d * 32;
  float4 l0 = *reinterpret_cast<const float4*>(hq);
  float4 l1 = *reinterpret_cast<const float4*>(hq + 4);

  union { u16 u[8]; bf16x8 v; } uL, uR;
  {
    float lf[8] = {l0.x, l0.y, l0.z, l0.w, l1.x, l1.y, l1.z, l1.w};
    float rf[8] = {r0.x, r0.y, r0.z, r0.w, r1.x, r1.y, r1.z, r1.w};
    #pragma unroll
    for (int j = 0; j < 8; j++) { uL.u[j] = f2bf(lf[j]); uR.u[j] = f2bf(rf[j]); }
  }
  *reinterpret_cast<float4*>(&HRT[wv][pc][kg * 8]) = r0;
  *reinterpret_cast<float4*>(&HRT[wv][pc][kg * 8 + 4]) = r1;

  f32x4 cs0 = {0.f, 0.f, 0.f, 0.f}, cs1 = {0.f, 0.f, 0.f, 0.f};
  f32x4 ct0 = {0.f, 0.f, 0.f, 0.f}, ct1 = {0.f, 0.f, 0.f, 0.f};
  cs0 = __builtin_amdgcn_mfma_f32_16x16x32_bf16(AW[0][0], uL.v, cs0, 0, 0, 0);
  cs0 = __builtin_amdgcn_mfma_f32_16x16x32_bf16(AW[0][1], uR.v, cs0, 0, 0, 0);
  cs1 = __builtin_amdgcn_mfma_f32_16x16x32_bf16(AW[1][0], uL.v, cs1, 0, 0, 0);
  cs1 = __builtin_amdgcn_mfma_f32_16x16x32_bf16(AW[1][1], uR.v, cs1, 0, 0, 0);
  ct0 = __builtin_amdgcn_mfma_f32_16x16x32_bf16(AW[2][0], uL.v, ct0, 0, 0, 0);
  ct0 = __builtin_amdgcn_mfma_f32_16x16x32_bf16(AW[2][1], uR.v, ct0, 0, 0, 0);
  ct1 = __builtin_amdgcn_mfma_f32_16x16x32_bf16(AW[3][0], uL.v, ct1, 0, 0, 0);
  ct1 = __builtin_amdgcn_mfma_f32_16x16x32_bf16(AW[3][1], uR.v, ct1, 0, 0, 0);

  u16 gs0[4], gs1[4];
  {
    float sa[4] = {sbv0.x, sbv0.y, sbv0.z, sbv0.w};
    float sbq[4] = {sbv1.x, sbv1.y, sbv1.z, sbv1.w};
    float ta[4] = {tbv0.x, tbv0.y, tbv0.z, tbv0.w};
    float tbq[4] = {tbv1.x, tbv1.y, tbv1.z, tbv1.w};
    #pragma unroll
    for (int r = 0; r < 4; r++) {
      float s0 = cs0[r] + sa[r], t0v = ct0[r] + ta[r];
      float s1 = cs1[r] + sbq[r], t1v = ct1[r] + tbq[r];
      float g0 = (1.f / (1.f + __expf(-s0))) * (2.f / (1.f + __expf(-2.f * t0v)) - 1.f);
      float g1 = (1.f / (1.f + __expf(-s1))) * (2.f / (1.f + __expf(-2.f * t1v)) - 1.f);
      gs0[r] = f2bf(g0);
      gs1[r] = f2bf(g1);
    }
  }
  uint2 pk0 = {(unsigned)gs0[0] | ((unsigned)gs0[1] << 16),
               (unsigned)gs0[2] | ((unsigned)gs0[3] << 16)};
  uint2 pk1 = {(unsigned)gs1[0] | ((unsigned)gs1[1] << 16),
               (unsigned)gs1[2] | ((unsigned)gs1[3] << 16)};
  *reinterpret_cast<uint2*>(&GT[wv][pc][kg * 4]) = pk0;
  *reinterpret_cast<uint2*>(&GT[wv][pc][16 + kg * 4]) = pk1;

  if (valid && p >= cw - clen) {
    int n = b * clen + (p - (cw - clen));
    u16* gr = G + (size_t)n * K1 + layer * 32;
    *reinterpret_cast<uint2*>(gr + kg * 4) = pk0;
    *reinterpret_cast<uint2*>(gr + 16 + kg * 4) = pk1;
  }

  bf16x8 bg = *reinterpret_cast<const bf16x8*>(&GT[wv][pc][kg * 8]);
  float4 ha = *reinterpret_cast<const float4*>(&HRT[wv][pc][kg * 4]);
  float4 hbq = *reinterpret_cast<const float4*>(&HRT[wv][pc][16 + kg * 4]);
  f32x4 h0 = {ha.x + rbv0.x, ha.y + rbv0.y, ha.z + rbv0.z, ha.w + rbv0.w};
  f32x4 h1 = {hbq.x + rbv1.x, hbq.y + rbv1.y, hbq.z + rbv1.z, hbq.w + rbv1.w};
  f32x4 d0 = __builtin_amdgcn_mfma_f32_16x16x32_bf16(AR[0], bg, h0, 0, 0, 0);
  f32x4 d1 = __builtin_amdgcn_mfma_f32_16x16x32_bf16(AR[1], bg, h1, 0, 0, 0);
  if (valid) {
    float* dp = dst + ((size_t)b * cw + p) * 32;
    *reinterpret_cast<float4*>(dp + kg * 4) = float4{d0[0], d0[1], d0[2], d0[3]};
    *reinterpret_cast<float4*>(dp + 16 + kg * 4) = float4{d1[0], d1[1], d1[2], d1[3]};
  }
}

// ---------- bf16 MFMA GEMM, BK=64, reg-staged (round-8 proven), XCD-swizzled ----------
// A: [512][K] bf16. B: [N][K] bf16 (BT). FIN=0: Out[col][512] = bf16(elu(acc+bias)).
// FIN=1: fused post2 dot -> atomicAdd into outv (pre-zeroed).
__global__ __launch_bounds__(256) void gemm_k(
    const u16* __restrict__ A, const u16* __restrict__ B,
    const float* __restrict__ bias, u16* __restrict__ Out,
    const float* __restrict__ w2, const float* __restrict__ b2p,
    float* __restrict__ outv,
    int N, int K, int FIN, int clen, int t0f) {
  __shared__ u16 As[128][72];
  __shared__ u16 Bs[128][72];
  int tid = threadIdx.x;

  int nwg = gridDim.x;
  int orig = blockIdx.x;
  int q = nwg >> 3, r8 = nwg & 7, xcd = orig & 7, sl = orig >> 3;
  int wg = (xcd < r8 ? xcd * (q + 1) : r8 * (q + 1) + (xcd - r8) * q) + sl;
  int m0 = (wg & 3) * 128;
  int n0 = (wg >> 2) * 128;

  int lane = tid & 63, wv = tid >> 6;
  int wm = wv >> 1, wn = wv & 1;
  int row16 = lane & 15, kg = lane >> 4;

  f32x4 acc[4][4];
  #pragma unroll
  for (int i = 0; i < 4; i++)
    #pragma unroll
    for (int j = 0; j < 4; j++) acc[i][j] = f32x4{0.f, 0.f, 0.f, 0.f};

  int rS = tid >> 1, qS = tid & 1;
  for (int k0 = 0; k0 < K; k0 += 64) {
    {
      const uint4* asrc = reinterpret_cast<const uint4*>(A + (size_t)(m0 + rS) * K + k0 + qS * 32);
      uint4 a0 = asrc[0], a1 = asrc[1], a2 = asrc[2], a3 = asrc[3];
      *reinterpret_cast<uint4*>(&As[rS][qS * 32]) = a0;
      *reinterpret_cast<uint4*>(&As[rS][qS * 32 + 8]) = a1;
      *reinterpret_cast<uint4*>(&As[rS][qS * 32 + 16]) = a2;
      *reinterpret_cast<uint4*>(&As[rS][qS * 32 + 24]) = a3;
    }
    {
      int nr = n0 + rS;
      uint4 b0 = {0,0,0,0}, b1 = {0,0,0,0}, b2 = {0,0,0,0}, b3 = {0,0,0,0};
      if (nr < N) {
        const uint4* bsrc = reinterpret_cast<const uint4*>(B + (size_t)nr * K + k0 + qS * 32);
        b0 = bsrc[0]; b1 = bsrc[1]; b2 = bsrc[2]; b3 = bsrc[3];
      }
      *reinterpret_cast<uint4*>(&Bs[rS][qS * 32]) = b0;
      *reinterpret_cast<uint4*>(&Bs[rS][qS * 32 + 8]) = b1;
      *reinterpret_cast<uint4*>(&Bs[rS][qS * 32 + 16]) = b2;
      *reinterpret_cast<uint4*>(&Bs[rS][qS * 32 + 24]) = b3;
    }
    __syncthreads();

    #pragma unroll
    for (int s = 0; s < 2; s++) {
      bf16x8 af[4], bfr[4];
      #pragma unroll
      for (int mf = 0; mf < 4; mf++)
        af[mf] = *reinterpret_cast<const bf16x8*>(&As[wm * 64 + mf * 16 + row16][s * 32 + kg * 8]);
      #pragma unroll
      for (int nf = 0; nf < 4; nf++)
        bfr[nf] = *reinterpret_cast<const bf16x8*>(&Bs[wn * 64 + nf * 16 + row16][s * 32 + kg * 8]);
      #pragma unroll
      for (int mf = 0; mf < 4; mf++)
        #pragma unroll
        for (int nf = 0; nf < 4; nf++)
          acc[mf][nf] = __builtin_amdgcn_mfma_f32_16x16x32_bf16(af[mf], bfr[nf], acc[mf][nf], 0, 0, 0);
    }
    __syncthreads();
  }

  if (!FIN) {
    #pragma unroll
    for (int mf = 0; mf < 4; mf++) {
      int rowb = m0 + wm * 64 + mf * 16 + kg * 4;
      float b0 = bias[rowb], b1 = bias[rowb + 1], b2 = bias[rowb + 2], b3 = bias[rowb + 3];
      #pragma unroll
      for (int nf = 0; nf < 4; nf++) {
        int col = n0 + wn * 64 + nf * 16 + row16;
        if (col < N) {
          float v0 = acc[mf][nf][0] + b0, v1 = acc[mf][nf][1] + b1;
          float v2 = acc[mf][nf][2] + b2, v3 = acc[mf][nf][3] + b3;
          v0 = v0 > 0.f ? v0 : expm1f(v0);
          v1 = v1 > 0.f ? v1 : expm1f(v1);
          v2 = v2 > 0.f ? v2 : expm1f(v2);
          v3 = v3 > 0.f ? v3 : expm1f(v3);
          uint2 pk = {(unsigned)f2bf(v0) | ((unsigned)f2bf(v1) << 16),
                      (unsigned)f2bf(v2) | ((unsigned)f2bf(v3) << 16)};
          *reinterpret_cast<uint2*>(Out + (size_t)col * 512 + rowb) = pk;
        }
      }
    }
  } else {
    float part[4] = {0.f, 0.f, 0.f, 0.f};
    #pragma unroll
    for (int mf = 0; mf < 4; mf++) {
      int rowb = m0 + wm * 64 + mf * 16 + kg * 4;
      float b0 = bias[rowb], b1 = bias[rowb + 1], b2 = bias[rowb + 2], b3 = bias[rowb + 3];
      float w0 = w2[rowb], w1 = w2[rowb + 1], w2v = w2[rowb + 2], w3 = w2[rowb + 3];
      #pragma unroll
      for (int nf = 0; nf < 4; nf++) {
        float v0 = acc[mf][nf][0] + b0, v1 = acc[mf][nf][1] + b1;
        float v2 = acc[mf][nf][2] + b2, v3 = acc[mf][nf][3] + b3;
        v0 = v0 > 0.f ? v0 : expm1f(v0);
        v1 = v1 > 0.f ? v1 : expm1f(v1);
        v2 = v2 > 0.f ? v2 : expm1f(v2);
        v3 = v3 > 0.f ? v3 : expm1f(v3);
        part[nf] += w0 * v0 + w1 * v1 + w2v * v2 + w3 * v3;
      }
    }
    #pragma unroll
    for (int nf = 0; nf < 4; nf++) {
      float p = part[nf];
      p += __shfl_xor(p, 16);
      p += __shfl_xor(p, 32);
      if (kg == 0) {
        int col = n0 + wn * 64 + nf * 16 + row16;
        if (col < N) {
          if (m0 == 0 && wm == 0) p += b2p[0];
          int bb = col / clen, tc = col - bb * clen;
          atomicAdd(outv + (size_t)bb * LOUT + t0f + tc, p);
        }
      }
    }
  }
}

extern "C" void kernel_launch(void* const* d_in, const int* in_sizes, int n_in,
                              void* d_out, int out_size, void* d_ws, size_t ws_size,
                              hipStream_t stream) {
  const float* input   = (const float*)d_in[0];
  const float* from_w  = (const float*)d_in[1];
  const float* from_b  = (const float*)d_in[2];
  const float* sig_w   = (const float*)d_in[3];
  const float* sig_b   = (const float*)d_in[4];
  const float* tan_w   = (const float*)d_in[5];
  const float* tan_b   = (const float*)d_in[6];
  const float* skip_w  = (const float*)d_in[7];
  const float* skip_b  = (const float*)d_in[8];
  const float* res_w   = (const float*)d_in[9];
  const float* res_b   = (const float*)d_in[10];
  const float* post1_w = (const float*)d_in[11];
  const float* post1_b = (const float*)d_in[12];
  const float* post2_w = (const float*)d_in[13];
  const float* post2_b = (const float*)d_in[14];

  auto al = [](size_t x) { return (x + 255) & ~(size_t)255; };
  size_t oW  = 0;
  size_t oP1 = oW  + al((size_t)512 * K1 * 2);
  size_t oB  = oP1 + al((size_t)512 * 512 * 2);
  size_t oWC = oB  + al((size_t)512 * 4);
  size_t oRC = oWC + al((size_t)NLAYER * 64 * 64 * 2);
  size_t wend = oRC + al((size_t)NLAYER * 32 * 32 * 2);

  int NC = 32, CL = 0;
  size_t oH0 = wend, oH1 = wend, oG = wend, oE = wend;
  const int cand[6] = {1, 2, 4, 8, 16, 32};
  for (int ci = 0; ci < 6; ci++) {
    int nc = cand[ci];
    int cl = (LOUT + nc - 1) / nc;
    int cw = cl + SUMD;
    size_t hB = al((size_t)NB * 32 * cw * 4);
    size_t gB = al((size_t)NB * cl * K1 * 2);
    size_t eB = al((size_t)512 * NB * cl * 2);
    size_t need = wend + 2 * hB + gB + eB;
    if (need <= ws_size || nc == 32) {
      NC = nc; CL = cl;
      oH0 = wend; oH1 = oH0 + hB; oG = oH1 + hB; oE = oG + gB;
      break;
    }
  }

  char* ws = (char*)d_ws;
  u16*   Wskip = (u16*)(ws + oW);
  u16*   P1    = (u16*)(ws + oP1);
  float* biasS = (float*)(ws + oB);
  u16*   WC    = (u16*)(ws + oWC);
  u16*   RC    = (u16*)(ws + oRC);
  float* H0    = (float*)(ws + oH0);
  float* H1    = (float*)(ws + oH1);
  u16*   G     = (u16*)(ws + oG);
  u16*   E     = (u16*)(ws + oE);

  hipMemsetAsync(d_out, 0, (size_t)out_size * sizeof(float), stream);

  int prep_items = 512 * K1 + 512 * 512 + 512 + NLAYER * 64 * 64 + NLAYER * 32 * 32;
  prep_k<<<(prep_items + 255) / 256, 256, 0, stream>>>(
      skip_w, skip_b, post1_w, sig_w, tan_w, res_w, Wskip, P1, biasS, WC, RC);

  for (int c = 0; c < NC; c++) {
    int t0 = c * CL;
    if (t0 >= LOUT) break;
    int clen = LOUT - t0 < CL ? LOUT - t0 : CL;
    int cw = clen + SUMD;

    init_p<<<256, 256, 0, stream>>>(input, from_w, from_b, H0, t0, cw);

    float* a = H0;
    float* b2 = H1;
    int len = cw;
    for (int cyc = 0; cyc < 5; cyc++) {
      int L0 = cyc * 10;
      int lo8 = len - 255;
      int tiles = (lo8 + FWOUT - 1) / FWOUT;
      fuse8_k<<<dim3(tiles, NB), 1024, 0, stream>>>(
          a, b2, G, WC, RC, sig_b, tan_b, res_b, L0, len, cw, clen);
      { float* t = a; a = b2; b2 = t; }
      len = lo8;
      for (int j = 0; j < 2; j++) {
        int li = L0 + 8 + j, d = 256 << j;
        int lo = len - d;
        layer_p<<<dim3((lo + 63) / 64, NB), 256, 0, stream>>>(
            a, b2, G, WC + (size_t)li * 4096, RC + (size_t)li * 1024,
            sig_b + li * 32, tan_b + li * 32, res_b + li * 32,
            li, d, lo, cw, clen);
        { float* t = a; a = b2; b2 = t; }
        len = lo;
      }
    }

    int Nc = NB * clen;
    int ntile = (Nc + 127) / 128;
    gemm_k<<<4 * ntile, 256, 0, stream>>>(Wskip, G, biasS, E,
                                          post2_w, post2_b, (float*)d_out,
                                          Nc, K1, 0, clen, t0);
    gemm_k<<<4 * ntile, 256, 0, stream>>>(P1, E, post1_b, E,
                                          post2_w, post2_b, (float*)d_out,
                                          Nc, 512, 1, clen, t0);
  }
}

// Round 11
// 648.663 us; speedup vs baseline: 1.1433x; 1.1433x over previous
//
#include <hip/hip_runtime.h>
#include <hip/hip_bf16.h>

#define TLEN 16384
#define NB 4
#define NLAYER 50
#define SUMD 5115
#define LOUT 11269                  // TLEN - SUMD
#define K1 (NLAYER * 32)            // 1600
#define MSKIP 512
#define FWOUT 256                   // fused-kernel owned points per block
#define FWIN 511                    // FWOUT + 255 halo
#define FP 34                       // padded LDS row stride (floats); 34%32=2 -> distinct banks

typedef unsigned short u16;
typedef __attribute__((ext_vector_type(4))) float f32x4;
typedef __attribute__((ext_vector_type(8))) __bf16 bf16x8;

__device__ __forceinline__ u16 f2bf(float f) {
  __hip_bfloat16 h = __float2bfloat16(f);
  return *reinterpret_cast<u16*>(&h);
}
__device__ __forceinline__ float bf2f(u16 u) {
  __hip_bfloat16 h = *reinterpret_cast<__hip_bfloat16*>(&u);
  return __bfloat162float(h);
}
// gate = sigmoid(s)*tanh(t) via hw exp2/rcp (no fp32 div sequences)
__device__ __forceinline__ float gatef(float s, float t) {
  float es = __builtin_amdgcn_exp2f(s * -1.442695041f);      // e^-s
  float sig = __builtin_amdgcn_rcpf(1.f + es);
  float et = __builtin_amdgcn_exp2f(t * -2.885390082f);      // e^-2t
  float th = 2.f * __builtin_amdgcn_rcpf(1.f + et) - 1.f;
  return sig * th;
}

// ---------- prep: convert/pack weights (once per call) ----------
__global__ __launch_bounds__(256) void prep_k(
    const float* __restrict__ skip_w, const float* __restrict__ skip_b,
    const float* __restrict__ post1_w,
    const float* __restrict__ sig_w, const float* __restrict__ tan_w,
    const float* __restrict__ res_w,
    u16* __restrict__ Wskip, u16* __restrict__ P1, float* __restrict__ biasS,
    u16* __restrict__ WC, u16* __restrict__ RC) {
  int t = blockIdx.x * 256 + threadIdx.x;
  const int n1 = 512 * K1;
  const int n2 = n1 + 512 * 512;
  const int n3 = n2 + 512;
  const int n4 = n3 + NLAYER * 64 * 64;
  const int n5 = n4 + NLAYER * 32 * 32;
  if (t < n1) {
    int m = t / K1, k = t - m * K1;
    int i = k >> 5, c = k & 31;
    Wskip[t] = f2bf(skip_w[((size_t)i * 512 + m) * 32 + c]);
  } else if (t < n2) {
    int z = t - n1;
    P1[z] = f2bf(post1_w[z]);
  } else if (t < n3) {
    int c = t - n2;
    float s = 0.f;
    for (int i = 0; i < NLAYER; i++) s += skip_b[i * 512 + c];
    biasS[c] = s;
  } else if (t < n4) {
    int z = t - n3;
    int l = z >> 12, rem = z & 4095, o = rem >> 6, k = rem & 63;
    int c = k & 31, lr = k >> 5;
    float v;
    if (o < 32) v = sig_w[(((size_t)l * 32 + o) * 32 + c) * 2 + lr];
    else        v = tan_w[(((size_t)l * 32 + (o - 32)) * 32 + c) * 2 + lr];
    WC[z] = f2bf(v);
  } else if (t < n5) {
    int z = t - n4;
    int l = z >> 10, rem = z & 1023, o = rem >> 5, c = rem & 31;
    RC[z] = f2bf(res_w[((size_t)l * 32 + o) * 32 + c]);
  }
}

// ---------- init (point-major H [b][p][32]): h0 = from_w @ input + from_b ----------
__global__ __launch_bounds__(256) void init_p(
    const float* __restrict__ inp, const float* __restrict__ fw,
    const float* __restrict__ fb, float* __restrict__ H, int t0, int cw) {
  __shared__ float FWs[256];
  __shared__ float FBs[32];
  int tid = threadIdx.x;
  FWs[tid] = fw[tid];
  if (tid < 32) FBs[tid] = fb[tid];
  __syncthreads();
  int gsz = gridDim.x * 256;
  int gid0 = blockIdx.x * 256 + tid;
  for (int b = 0; b < NB; b++) {
    const float* ib = inp + ((size_t)b * TLEN + t0) * 8;
    float* hb = H + (size_t)b * cw * 32;
    for (int p = gid0; p < cw; p += gsz) {
      float4 x0 = *reinterpret_cast<const float4*>(ib + (size_t)p * 8);
      float4 x1 = *reinterpret_cast<const float4*>(ib + (size_t)p * 8 + 4);
      float x[8] = {x0.x, x0.y, x0.z, x0.w, x1.x, x1.y, x1.z, x1.w};
      float* op = hb + (size_t)p * 32;
      #pragma unroll
      for (int r4 = 0; r4 < 8; r4++) {
        float4 o;
        #pragma unroll
        for (int j = 0; j < 4; j++) {
          int r = r4 * 4 + j;
          float acc = FBs[r];
          #pragma unroll
          for (int f = 0; f < 8; f++) acc += FWs[r * 8 + f] * x[f];
          ((float*)&o)[j] = acc;
        }
        *reinterpret_cast<float4*>(op + r4 * 4) = o;
      }
    }
  }
}

// ---------- fused 8 small-dilation layers (d = 1..128, halo 255) in LDS ----------
// 1024 thr = 16 waves = 4 waves/SIMD at 1 block/CU (LDS 159.5 KB).
__global__ __launch_bounds__(1024, 1) void fuse8_k(
    const float* __restrict__ src, float* __restrict__ dst,
    u16* __restrict__ G,
    const u16* __restrict__ WC, const u16* __restrict__ RC,
    const float* __restrict__ sb, const float* __restrict__ tb,
    const float* __restrict__ rb,
    int L0, int len_in, int cw, int clen) {
  __shared__ float HB[2][FWIN][FP];   // 139.0 KB
  __shared__ u16 GT[16][16][40];      // 20.5 KB
  int tid = threadIdx.x;
  int wv = tid >> 6, lane = tid & 63;
  int pc = lane & 15, kg = lane >> 4;
  int b = blockIdx.y;
  int len_out = len_in - 255;
  int pstart = cw - len_out + blockIdx.x * FWOUT;
  int g0 = pstart - 255;
  int wcount = (cw - g0 < FWIN) ? (cw - g0) : FWIN;
  int ocount = (cw - pstart < FWOUT) ? (cw - pstart) : FWOUT;

  const float* sp = src + ((size_t)b * cw + g0) * 32;
  for (int z = tid; z < wcount * 8; z += 1024) {
    int lp = z >> 3, c4 = z & 7;
    *reinterpret_cast<float4*>(&HB[0][lp][c4 * 4]) =
        *reinterpret_cast<const float4*>(sp + (size_t)lp * 32 + c4 * 4);
  }
  __syncthreads();

  int cur = 0;
  for (int l = 0; l < 8; l++) {
    int d = 1 << l;
    int cumD = (2 << l) - 1;
    const u16* Wc = WC + (size_t)(L0 + l) * 4096;
    const u16* Rc = RC + (size_t)(L0 + l) * 1024;
    bf16x8 AW[4][2], AR[2];
    #pragma unroll
    for (int mt = 0; mt < 4; mt++) {
      AW[mt][0] = *reinterpret_cast<const bf16x8*>(Wc + (mt * 16 + pc) * 64 + kg * 8);
      AW[mt][1] = *reinterpret_cast<const bf16x8*>(Wc + (mt * 16 + pc) * 64 + 32 + kg * 8);
    }
    AR[0] = *reinterpret_cast<const bf16x8*>(Rc + pc * 32 + kg * 8);
    AR[1] = *reinterpret_cast<const bf16x8*>(Rc + (16 + pc) * 32 + kg * 8);
    float4 sbv0 = *reinterpret_cast<const float4*>(sb + (L0 + l) * 32 + kg * 4);
    float4 sbv1 = *reinterpret_cast<const float4*>(sb + (L0 + l) * 32 + 16 + kg * 4);
    float4 tbv0 = *reinterpret_cast<const float4*>(tb + (L0 + l) * 32 + kg * 4);
    float4 tbv1 = *reinterpret_cast<const float4*>(tb + (L0 + l) * 32 + 16 + kg * 4);
    float4 rbv0 = *reinterpret_cast<const float4*>(rb + (L0 + l) * 32 + kg * 4);
    float4 rbv1 = *reinterpret_cast<const float4*>(rb + (L0 + l) * 32 + 16 + kg * 4);

    int lo_local = wcount - cumD;
    int nit = (lo_local + 255) >> 8;    // 16 waves x 16 pts = 256/iter
    for (int t = 0; t < nit; t++) {
      int lp = cumD + t * 256 + wv * 16 + pc;
      bool valid = lp < wcount;
      int lpc = valid ? lp : wcount - 1;

      float4 r0 = *reinterpret_cast<const float4*>(&HB[cur][lpc][kg * 8]);
      float4 r1 = *reinterpret_cast<const float4*>(&HB[cur][lpc][kg * 8 + 4]);
      float4 l0v = *reinterpret_cast<const float4*>(&HB[cur][lpc - d][kg * 8]);
      float4 l1v = *reinterpret_cast<const float4*>(&HB[cur][lpc - d][kg * 8 + 4]);

      union { u16 u[8]; bf16x8 v; } uL, uR;
      {
        float lf[8] = {l0v.x, l0v.y, l0v.z, l0v.w, l1v.x, l1v.y, l1v.z, l1v.w};
        float rf[8] = {r0.x, r0.y, r0.z, r0.w, r1.x, r1.y, r1.z, r1.w};
        #pragma unroll
        for (int j = 0; j < 8; j++) { uL.u[j] = f2bf(lf[j]); uR.u[j] = f2bf(rf[j]); }
      }

      f32x4 cs0 = {0.f, 0.f, 0.f, 0.f}, cs1 = {0.f, 0.f, 0.f, 0.f};
      f32x4 ct0 = {0.f, 0.f, 0.f, 0.f}, ct1 = {0.f, 0.f, 0.f, 0.f};
      cs0 = __builtin_amdgcn_mfma_f32_16x16x32_bf16(AW[0][0], uL.v, cs0, 0, 0, 0);
      cs0 = __builtin_amdgcn_mfma_f32_16x16x32_bf16(AW[0][1], uR.v, cs0, 0, 0, 0);
      cs1 = __builtin_amdgcn_mfma_f32_16x16x32_bf16(AW[1][0], uL.v, cs1, 0, 0, 0);
      cs1 = __builtin_amdgcn_mfma_f32_16x16x32_bf16(AW[1][1], uR.v, cs1, 0, 0, 0);
      ct0 = __builtin_amdgcn_mfma_f32_16x16x32_bf16(AW[2][0], uL.v, ct0, 0, 0, 0);
      ct0 = __builtin_amdgcn_mfma_f32_16x16x32_bf16(AW[2][1], uR.v, ct0, 0, 0, 0);
      ct1 = __builtin_amdgcn_mfma_f32_16x16x32_bf16(AW[3][0], uL.v, ct1, 0, 0, 0);
      ct1 = __builtin_amdgcn_mfma_f32_16x16x32_bf16(AW[3][1], uR.v, ct1, 0, 0, 0);

      u16 gs0[4], gs1[4];
      {
        float sa[4] = {sbv0.x, sbv0.y, sbv0.z, sbv0.w};
        float sbq[4] = {sbv1.x, sbv1.y, sbv1.z, sbv1.w};
        float ta[4] = {tbv0.x, tbv0.y, tbv0.z, tbv0.w};
        float tbq[4] = {tbv1.x, tbv1.y, tbv1.z, tbv1.w};
        #pragma unroll
        for (int r = 0; r < 4; r++) {
          gs0[r] = f2bf(gatef(cs0[r] + sa[r], ct0[r] + ta[r]));
          gs1[r] = f2bf(gatef(cs1[r] + sbq[r], ct1[r] + tbq[r]));
        }
      }
      uint2 pk0 = {(unsigned)gs0[0] | ((unsigned)gs0[1] << 16),
                   (unsigned)gs0[2] | ((unsigned)gs0[3] << 16)};
      uint2 pk1 = {(unsigned)gs1[0] | ((unsigned)gs1[1] << 16),
                   (unsigned)gs1[2] | ((unsigned)gs1[3] << 16)};
      *reinterpret_cast<uint2*>(&GT[wv][pc][kg * 4]) = pk0;
      *reinterpret_cast<uint2*>(&GT[wv][pc][16 + kg * 4]) = pk1;

      int p = g0 + lpc;
      if (valid && p >= pstart && p < pstart + ocount && p >= cw - clen) {
        int n = b * clen + (p - (cw - clen));
        u16* gr = G + (size_t)n * K1 + (L0 + l) * 32;
        *reinterpret_cast<uint2*>(gr + kg * 4) = pk0;
        *reinterpret_cast<uint2*>(gr + 16 + kg * 4) = pk1;
      }

      bf16x8 bg = *reinterpret_cast<const bf16x8*>(&GT[wv][pc][kg * 8]);
      float4 ha = *reinterpret_cast<const float4*>(&HB[cur][lpc][kg * 4]);
      float4 hb2 = *reinterpret_cast<const float4*>(&HB[cur][lpc][16 + kg * 4]);
      f32x4 h0 = {ha.x + rbv0.x, ha.y + rbv0.y, ha.z + rbv0.z, ha.w + rbv0.w};
      f32x4 h1 = {hb2.x + rbv1.x, hb2.y + rbv1.y, hb2.z + rbv1.z, hb2.w + rbv1.w};
      f32x4 d0 = __builtin_amdgcn_mfma_f32_16x16x32_bf16(AR[0], bg, h0, 0, 0, 0);
      f32x4 d1 = __builtin_amdgcn_mfma_f32_16x16x32_bf16(AR[1], bg, h1, 0, 0, 0);
      if (valid) {
        *reinterpret_cast<float4*>(&HB[cur ^ 1][lp][kg * 4]) = float4{d0[0], d0[1], d0[2], d0[3]};
        *reinterpret_cast<float4*>(&HB[cur ^ 1][lp][16 + kg * 4]) = float4{d1[0], d1[1], d1[2], d1[3]};
      }
    }
    __syncthreads();
    cur ^= 1;
  }

  float* dp = dst + ((size_t)b * cw + pstart) * 32;
  for (int z = tid; z < ocount * 8; z += 1024) {
    int lp = z >> 3, c4 = z & 7;
    *reinterpret_cast<float4*>(dp + (size_t)lp * 32 + c4 * 4) =
        *reinterpret_cast<float4*>(&HB[cur][255 + lp][c4 * 4]);
  }
}

// ---------- single big-dilation layer (point-major) ----------
__global__ __launch_bounds__(256, 2) void layer_p(
    const float* __restrict__ src, float* __restrict__ dst,
    u16* __restrict__ G,
    const u16* __restrict__ Wc, const u16* __restrict__ Rc,
    const float* __restrict__ sbl, const float* __restrict__ tbl,
    const float* __restrict__ rbl,
    int layer, int d, int lo, int cw, int clen) {
  __shared__ u16 GT[4][16][40];
  __shared__ float HRT[4][16][36];
  int tid = threadIdx.x;
  int wv = tid >> 6, lane = tid & 63;
  int pc = lane & 15, kg = lane >> 4;
  int b = blockIdx.y;

  bf16x8 AW[4][2], AR[2];
  #pragma unroll
  for (int mt = 0; mt < 4; mt++) {
    AW[mt][0] = *reinterpret_cast<const bf16x8*>(Wc + (mt * 16 + pc) * 64 + kg * 8);
    AW[mt][1] = *reinterpret_cast<const bf16x8*>(Wc + (mt * 16 + pc) * 64 + 32 + kg * 8);
  }
  AR[0] = *reinterpret_cast<const bf16x8*>(Rc + pc * 32 + kg * 8);
  AR[1] = *reinterpret_cast<const bf16x8*>(Rc + (16 + pc) * 32 + kg * 8);

  float4 sbv0 = *reinterpret_cast<const float4*>(sbl + kg * 4);
  float4 sbv1 = *reinterpret_cast<const float4*>(sbl + 16 + kg * 4);
  float4 tbv0 = *reinterpret_cast<const float4*>(tbl + kg * 4);
  float4 tbv1 = *reinterpret_cast<const float4*>(tbl + 16 + kg * 4);
  float4 rbv0 = *reinterpret_cast<const float4*>(rbl + kg * 4);
  float4 rbv1 = *reinterpret_cast<const float4*>(rbl + 16 + kg * 4);

  int idx = blockIdx.x * 64 + wv * 16 + pc;
  bool valid = idx < lo;
  int idc = valid ? idx : lo - 1;
  int p = cw - lo + idc;

  const float* hp = src + ((size_t)b * cw + p) * 32 + kg * 8;
  float4 r0 = *reinterpret_cast<const float4*>(hp);
  float4 r1 = *reinterpret_cast<const float4*>(hp + 4);
  const float* hq = hp - (size_t)d * 32;
  float4 l0 = *reinterpret_cast<const float4*>(hq);
  float4 l1 = *reinterpret_cast<const float4*>(hq + 4);

  union { u16 u[8]; bf16x8 v; } uL, uR;
  {
    float lf[8] = {l0.x, l0.y, l0.z, l0.w, l1.x, l1.y, l1.z, l1.w};
    float rf[8] = {r0.x, r0.y, r0.z, r0.w, r1.x, r1.y, r1.z, r1.w};
    #pragma unroll
    for (int j = 0; j < 8; j++) { uL.u[j] = f2bf(lf[j]); uR.u[j] = f2bf(rf[j]); }
  }
  *reinterpret_cast<float4*>(&HRT[wv][pc][kg * 8]) = r0;
  *reinterpret_cast<float4*>(&HRT[wv][pc][kg * 8 + 4]) = r1;

  f32x4 cs0 = {0.f, 0.f, 0.f, 0.f}, cs1 = {0.f, 0.f, 0.f, 0.f};
  f32x4 ct0 = {0.f, 0.f, 0.f, 0.f}, ct1 = {0.f, 0.f, 0.f, 0.f};
  cs0 = __builtin_amdgcn_mfma_f32_16x16x32_bf16(AW[0][0], uL.v, cs0, 0, 0, 0);
  cs0 = __builtin_amdgcn_mfma_f32_16x16x32_bf16(AW[0][1], uR.v, cs0, 0, 0, 0);
  cs1 = __builtin_amdgcn_mfma_f32_16x16x32_bf16(AW[1][0], uL.v, cs1, 0, 0, 0);
  cs1 = __builtin_amdgcn_mfma_f32_16x16x32_bf16(AW[1][1], uR.v, cs1, 0, 0, 0);
  ct0 = __builtin_amdgcn_mfma_f32_16x16x32_bf16(AW[2][0], uL.v, ct0, 0, 0, 0);
  ct0 = __builtin_amdgcn_mfma_f32_16x16x32_bf16(AW[2][1], uR.v, ct0, 0, 0, 0);
  ct1 = __builtin_amdgcn_mfma_f32_16x16x32_bf16(AW[3][0], uL.v, ct1, 0, 0, 0);
  ct1 = __builtin_amdgcn_mfma_f32_16x16x32_bf16(AW[3][1], uR.v, ct1, 0, 0, 0);

  u16 gs0[4], gs1[4];
  {
    float sa[4] = {sbv0.x, sbv0.y, sbv0.z, sbv0.w};
    float sbq[4] = {sbv1.x, sbv1.y, sbv1.z, sbv1.w};
    float ta[4] = {tbv0.x, tbv0.y, tbv0.z, tbv0.w};
    float tbq[4] = {tbv1.x, tbv1.y, tbv1.z, tbv1.w};
    #pragma unroll
    for (int r = 0; r < 4; r++) {
      gs0[r] = f2bf(gatef(cs0[r] + sa[r], ct0[r] + ta[r]));
      gs1[r] = f2bf(gatef(cs1[r] + sbq[r], ct1[r] + tbq[r]));
    }
  }
  uint2 pk0 = {(unsigned)gs0[0] | ((unsigned)gs0[1] << 16),
               (unsigned)gs0[2] | ((unsigned)gs0[3] << 16)};
  uint2 pk1 = {(unsigned)gs1[0] | ((unsigned)gs1[1] << 16),
               (unsigned)gs1[2] | ((unsigned)gs1[3] << 16)};
  *reinterpret_cast<uint2*>(&GT[wv][pc][kg * 4]) = pk0;
  *reinterpret_cast<uint2*>(&GT[wv][pc][16 + kg * 4]) = pk1;

  if (valid && p >= cw - clen) {
    int n = b * clen + (p - (cw - clen));
    u16* gr = G + (size_t)n * K1 + layer * 32;
    *reinterpret_cast<uint2*>(gr + kg * 4) = pk0;
    *reinterpret_cast<uint2*>(gr + 16 + kg * 4) = pk1;
  }

  bf16x8 bg = *reinterpret_cast<const bf16x8*>(&GT[wv][pc][kg * 8]);
  float4 ha = *reinterpret_cast<const float4*>(&HRT[wv][pc][kg * 4]);
  float4 hbq = *reinterpret_cast<const float4*>(&HRT[wv][pc][16 + kg * 4]);
  f32x4 h0 = {ha.x + rbv0.x, ha.y + rbv0.y, ha.z + rbv0.z, ha.w + rbv0.w};
  f32x4 h1 = {hbq.x + rbv1.x, hbq.y + rbv1.y, hbq.z + rbv1.z, hbq.w + rbv1.w};
  f32x4 d0 = __builtin_amdgcn_mfma_f32_16x16x32_bf16(AR[0], bg, h0, 0, 0, 0);
  f32x4 d1 = __builtin_amdgcn_mfma_f32_16x16x32_bf16(AR[1], bg, h1, 0, 0, 0);
  if (valid) {
    float* dp = dst + ((size_t)b * cw + p) * 32;
    *reinterpret_cast<float4*>(dp + kg * 4) = float4{d0[0], d0[1], d0[2], d0[3]};
    *reinterpret_cast<float4*>(dp + 16 + kg * 4) = float4{d1[0], d1[1], d1[2], d1[3]};
  }
}

// ---------- bf16 MFMA GEMM, BK=64, reg-staged, XCD-swizzled (lean, no FIN) ----------
// Out[col][512] = bf16(elu(A@B^T + bias)), A [512][K], B [N][K].
__global__ __launch_bounds__(256) void gemm_k(
    const u16* __restrict__ A, const u16* __restrict__ B,
    const float* __restrict__ bias, u16* __restrict__ Out,
    int N, int K) {
  __shared__ u16 As[128][72];
  __shared__ u16 Bs[128][72];
  int tid = threadIdx.x;

  int nwg = gridDim.x;
  int orig = blockIdx.x;
  int q = nwg >> 3, r8 = nwg & 7, xcd = orig & 7, sl = orig >> 3;
  int wg = (xcd < r8 ? xcd * (q + 1) : r8 * (q + 1) + (xcd - r8) * q) + sl;
  int m0 = (wg & 3) * 128;
  int n0 = (wg >> 2) * 128;

  int lane = tid & 63, wv = tid >> 6;
  int wm = wv >> 1, wn = wv & 1;
  int row16 = lane & 15, kg = lane >> 4;

  f32x4 acc[4][4];
  #pragma unroll
  for (int i = 0; i < 4; i++)
    #pragma unroll
    for (int j = 0; j < 4; j++) acc[i][j] = f32x4{0.f, 0.f, 0.f, 0.f};

  int rS = tid >> 1, qS = tid & 1;
  for (int k0 = 0; k0 < K; k0 += 64) {
    {
      const uint4* asrc = reinterpret_cast<const uint4*>(A + (size_t)(m0 + rS) * K + k0 + qS * 32);
      uint4 a0 = asrc[0], a1 = asrc[1], a2 = asrc[2], a3 = asrc[3];
      *reinterpret_cast<uint4*>(&As[rS][qS * 32]) = a0;
      *reinterpret_cast<uint4*>(&As[rS][qS * 32 + 8]) = a1;
      *reinterpret_cast<uint4*>(&As[rS][qS * 32 + 16]) = a2;
      *reinterpret_cast<uint4*>(&As[rS][qS * 32 + 24]) = a3;
    }
    {
      int nr = n0 + rS;
      uint4 b0 = {0,0,0,0}, b1 = {0,0,0,0}, b2 = {0,0,0,0}, b3 = {0,0,0,0};
      if (nr < N) {
        const uint4* bsrc = reinterpret_cast<const uint4*>(B + (size_t)nr * K + k0 + qS * 32);
        b0 = bsrc[0]; b1 = bsrc[1]; b2 = bsrc[2]; b3 = bsrc[3];
      }
      *reinterpret_cast<uint4*>(&Bs[rS][qS * 32]) = b0;
      *reinterpret_cast<uint4*>(&Bs[rS][qS * 32 + 8]) = b1;
      *reinterpret_cast<uint4*>(&Bs[rS][qS * 32 + 16]) = b2;
      *reinterpret_cast<uint4*>(&Bs[rS][qS * 32 + 24]) = b3;
    }
    __syncthreads();

    #pragma unroll
    for (int s = 0; s < 2; s++) {
      bf16x8 af[4], bfr[4];
      #pragma unroll
      for (int mf = 0; mf < 4; mf++)
        af[mf] = *reinterpret_cast<const bf16x8*>(&As[wm * 64 + mf * 16 + row16][s * 32 + kg * 8]);
      #pragma unroll
      for (int nf = 0; nf < 4; nf++)
        bfr[nf] = *reinterpret_cast<const bf16x8*>(&Bs[wn * 64 + nf * 16 + row16][s * 32 + kg * 8]);
      #pragma unroll
      for (int mf = 0; mf < 4; mf++)
        #pragma unroll
        for (int nf = 0; nf < 4; nf++)
          acc[mf][nf] = __builtin_amdgcn_mfma_f32_16x16x32_bf16(af[mf], bfr[nf], acc[mf][nf], 0, 0, 0);
    }
    __syncthreads();
  }

  #pragma unroll
  for (int mf = 0; mf < 4; mf++) {
    int rowb = m0 + wm * 64 + mf * 16 + kg * 4;
    float b0 = bias[rowb], b1 = bias[rowb + 1], b2 = bias[rowb + 2], b3 = bias[rowb + 3];
    #pragma unroll
    for (int nf = 0; nf < 4; nf++) {
      int col = n0 + wn * 64 + nf * 16 + row16;
      if (col < N) {
        float v0 = acc[mf][nf][0] + b0, v1 = acc[mf][nf][1] + b1;
        float v2 = acc[mf][nf][2] + b2, v3 = acc[mf][nf][3] + b3;
        v0 = v0 > 0.f ? v0 : expm1f(v0);
        v1 = v1 > 0.f ? v1 : expm1f(v1);
        v2 = v2 > 0.f ? v2 : expm1f(v2);
        v3 = v3 > 0.f ? v3 : expm1f(v3);
        uint2 pk = {(unsigned)f2bf(v0) | ((unsigned)f2bf(v1) << 16),
                    (unsigned)f2bf(v2) | ((unsigned)f2bf(v3) << 16)};
        *reinterpret_cast<uint2*>(Out + (size_t)col * 512 + rowb) = pk;
      }
    }
  }
}

// ---------- gemm with fused post2 epilogue (separate kernel: lean regalloc for gemm_k) ----------
__global__ __launch_bounds__(256) void gemm_fin(
    const u16* __restrict__ A, const u16* __restrict__ B,
    const float* __restrict__ bias,
    const float* __restrict__ w2, const float* __restrict__ b2p,
    float* __restrict__ outv,
    int N, int K, int clen, int t0f) {
  __shared__ u16 As[128][72];
  __shared__ u16 Bs[128][72];
  int tid = threadIdx.x;

  int nwg = gridDim.x;
  int orig = blockIdx.x;
  int q = nwg >> 3, r8 = nwg & 7, xcd = orig & 7, sl = orig >> 3;
  int wg = (xcd < r8 ? xcd * (q + 1) : r8 * (q + 1) + (xcd - r8) * q) + sl;
  int m0 = (wg & 3) * 128;
  int n0 = (wg >> 2) * 128;

  int lane = tid & 63, wv = tid >> 6;
  int wm = wv >> 1, wn = wv & 1;
  int row16 = lane & 15, kg = lane >> 4;

  f32x4 acc[4][4];
  #pragma unroll
  for (int i = 0; i < 4; i++)
    #pragma unroll
    for (int j = 0; j < 4; j++) acc[i][j] = f32x4{0.f, 0.f, 0.f, 0.f};

  int rS = tid >> 1, qS = tid & 1;
  for (int k0 = 0; k0 < K; k0 += 64) {
    {
      const uint4* asrc = reinterpret_cast<const uint4*>(A + (size_t)(m0 + rS) * K + k0 + qS * 32);
      uint4 a0 = asrc[0], a1 = asrc[1], a2 = asrc[2], a3 = asrc[3];
      *reinterpret_cast<uint4*>(&As[rS][qS * 32]) = a0;
      *reinterpret_cast<uint4*>(&As[rS][qS * 32 + 8]) = a1;
      *reinterpret_cast<uint4*>(&As[rS][qS * 32 + 16]) = a2;
      *reinterpret_cast<uint4*>(&As[rS][qS * 32 + 24]) = a3;
    }
    {
      int nr = n0 + rS;
      uint4 b0 = {0,0,0,0}, b1 = {0,0,0,0}, b2 = {0,0,0,0}, b3 = {0,0,0,0};
      if (nr < N) {
        const uint4* bsrc = reinterpret_cast<const uint4*>(B + (size_t)nr * K + k0 + qS * 32);
        b0 = bsrc[0]; b1 = bsrc[1]; b2 = bsrc[2]; b3 = bsrc[3];
      }
      *reinterpret_cast<uint4*>(&Bs[rS][qS * 32]) = b0;
      *reinterpret_cast<uint4*>(&Bs[rS][qS * 32 + 8]) = b1;
      *reinterpret_cast<uint4*>(&Bs[rS][qS * 32 + 16]) = b2;
      *reinterpret_cast<uint4*>(&Bs[rS][qS * 32 + 24]) = b3;
    }
    __syncthreads();

    #pragma unroll
    for (int s = 0; s < 2; s++) {
      bf16x8 af[4], bfr[4];
      #pragma unroll
      for (int mf = 0; mf < 4; mf++)
        af[mf] = *reinterpret_cast<const bf16x8*>(&As[wm * 64 + mf * 16 + row16][s * 32 + kg * 8]);
      #pragma unroll
      for (int nf = 0; nf < 4; nf++)
        bfr[nf] = *reinterpret_cast<const bf16x8*>(&Bs[wn * 64 + nf * 16 + row16][s * 32 + kg * 8]);
      #pragma unroll
      for (int mf = 0; mf < 4; mf++)
        #pragma unroll
        for (int nf = 0; nf < 4; nf++)
          acc[mf][nf] = __builtin_amdgcn_mfma_f32_16x16x32_bf16(af[mf], bfr[nf], acc[mf][nf], 0, 0, 0);
    }
    __syncthreads();
  }

  float part[4] = {0.f, 0.f, 0.f, 0.f};
  #pragma unroll
  for (int mf = 0; mf < 4; mf++) {
    int rowb = m0 + wm * 64 + mf * 16 + kg * 4;
    float b0 = bias[rowb], b1 = bias[rowb + 1], b2 = bias[rowb + 2], b3 = bias[rowb + 3];
    float w0 = w2[rowb], w1 = w2[rowb + 1], w2v = w2[rowb + 2], w3 = w2[rowb + 3];
    #pragma unroll
    for (int nf = 0; nf < 4; nf++) {
      float v0 = acc[mf][nf][0] + b0, v1 = acc[mf][nf][1] + b1;
      float v2 = acc[mf][nf][2] + b2, v3 = acc[mf][nf][3] + b3;
      v0 = v0 > 0.f ? v0 : expm1f(v0);
      v1 = v1 > 0.f ? v1 : expm1f(v1);
      v2 = v2 > 0.f ? v2 : expm1f(v2);
      v3 = v3 > 0.f ? v3 : expm1f(v3);
      part[nf] += w0 * v0 + w1 * v1 + w2v * v2 + w3 * v3;
    }
  }
  #pragma unroll
  for (int nf = 0; nf < 4; nf++) {
    float p = part[nf];
    p += __shfl_xor(p, 16);
    p += __shfl_xor(p, 32);
    if (kg == 0) {
      int col = n0 + wn * 64 + nf * 16 + row16;
      if (col < N) {
        if (m0 == 0 && wm == 0) p += b2p[0];
        int bb = col / clen, tc = col - bb * clen;
        atomicAdd(outv + (size_t)bb * LOUT + t0f + tc, p);
      }
    }
  }
}

extern "C" void kernel_launch(void* const* d_in, const int* in_sizes, int n_in,
                              void* d_out, int out_size, void* d_ws, size_t ws_size,
                              hipStream_t stream) {
  const float* input   = (const float*)d_in[0];
  const float* from_w  = (const float*)d_in[1];
  const float* from_b  = (const float*)d_in[2];
  const float* sig_w   = (const float*)d_in[3];
  const float* sig_b   = (const float*)d_in[4];
  const float* tan_w   = (const float*)d_in[5];
  const float* tan_b   = (const float*)d_in[6];
  const float* skip_w  = (const float*)d_in[7];
  const float* skip_b  = (const float*)d_in[8];
  const float* res_w   = (const float*)d_in[9];
  const float* res_b   = (const float*)d_in[10];
  const float* post1_w = (const float*)d_in[11];
  const float* post1_b = (const float*)d_in[12];
  const float* post2_w = (const float*)d_in[13];
  const float* post2_b = (const float*)d_in[14];

  auto al = [](size_t x) { return (x + 255) & ~(size_t)255; };
  size_t oW  = 0;
  size_t oP1 = oW  + al((size_t)512 * K1 * 2);
  size_t oB  = oP1 + al((size_t)512 * 512 * 2);
  size_t oWC = oB  + al((size_t)512 * 4);
  size_t oRC = oWC + al((size_t)NLAYER * 64 * 64 * 2);
  size_t wend = oRC + al((size_t)NLAYER * 32 * 32 * 2);

  int NC = 32, CL = 0;
  size_t oH0 = wend, oH1 = wend, oG = wend, oE = wend;
  const int cand[6] = {1, 2, 4, 8, 16, 32};
  for (int ci = 0; ci < 6; ci++) {
    int nc = cand[ci];
    int cl = (LOUT + nc - 1) / nc;
    int cw = cl + SUMD;
    size_t hB = al((size_t)NB * 32 * cw * 4);
    size_t gB = al((size_t)NB * cl * K1 * 2);
    size_t eB = al((size_t)512 * NB * cl * 2);
    size_t need = wend + 2 * hB + gB + eB;
    if (need <= ws_size || nc == 32) {
      NC = nc; CL = cl;
      oH0 = wend; oH1 = oH0 + hB; oG = oH1 + hB; oE = oG + gB;
      break;
    }
  }

  char* ws = (char*)d_ws;
  u16*   Wskip = (u16*)(ws + oW);
  u16*   P1    = (u16*)(ws + oP1);
  float* biasS = (float*)(ws + oB);
  u16*   WC    = (u16*)(ws + oWC);
  u16*   RC    = (u16*)(ws + oRC);
  float* H0    = (float*)(ws + oH0);
  float* H1    = (float*)(ws + oH1);
  u16*   G     = (u16*)(ws + oG);
  u16*   E     = (u16*)(ws + oE);

  hipMemsetAsync(d_out, 0, (size_t)out_size * sizeof(float), stream);

  int prep_items = 512 * K1 + 512 * 512 + 512 + NLAYER * 64 * 64 + NLAYER * 32 * 32;
  prep_k<<<(prep_items + 255) / 256, 256, 0, stream>>>(
      skip_w, skip_b, post1_w, sig_w, tan_w, res_w, Wskip, P1, biasS, WC, RC);

  for (int c = 0; c < NC; c++) {
    int t0 = c * CL;
    if (t0 >= LOUT) break;
    int clen = LOUT - t0 < CL ? LOUT - t0 : CL;
    int cw = clen + SUMD;

    init_p<<<256, 256, 0, stream>>>(input, from_w, from_b, H0, t0, cw);

    float* a = H0;
    float* b2 = H1;
    int len = cw;
    for (int cyc = 0; cyc < 5; cyc++) {
      int L0 = cyc * 10;
      int lo8 = len - 255;
      int tiles = (lo8 + FWOUT - 1) / FWOUT;
      fuse8_k<<<dim3(tiles, NB), 1024, 0, stream>>>(
          a, b2, G, WC, RC, sig_b, tan_b, res_b, L0, len, cw, clen);
      { float* t = a; a = b2; b2 = t; }
      len = lo8;
      for (int j = 0; j < 2; j++) {
        int li = L0 + 8 + j, d = 256 << j;
        int lo = len - d;
        layer_p<<<dim3((lo + 63) / 64, NB), 256, 0, stream>>>(
            a, b2, G, WC + (size_t)li * 4096, RC + (size_t)li * 1024,
            sig_b + li * 32, tan_b + li * 32, res_b + li * 32,
            li, d, lo, cw, clen);
        { float* t = a; a = b2; b2 = t; }
        len = lo;
      }
    }

    int Nc = NB * clen;
    int ntile = (Nc + 127) / 128;
    gemm_k<<<4 * ntile, 256, 0, stream>>>(Wskip, G, biasS, E, Nc, K1);
    gemm_fin<<<4 * ntile, 256, 0, stream>>>(P1, E, post1_b,
                                            post2_w, post2_b, (float*)d_out,
                                            Nc, 512, clen, t0);
  }
}